// Round 1
// baseline (9571.613 us; speedup 1.0000x reference)
//
#include <hip/hip_runtime.h>
#include <stdint.h>

#define T_DIM 4096
#define N_DIM 32768
#define D_DIM 1024
#define KB 32
#define NITER (N_DIM / KB)
#define QB 16

typedef _Float16 f16;
typedef _Float16 f16x8 __attribute__((ext_vector_type(8)));
typedef float f32x4 __attribute__((ext_vector_type(4)));

struct __align__(16) Lds {
  f16   Vs[1024][32];        // 64 KiB : V tile, Vs[d][k] = E[kbase+k][d]
  float Spart[8][32][16];    // 16 KiB : per-wave partial scores [wave][key][q]
  f16   Plds[16][32];        //  1 KiB : P[q][key]
  float wredmax[8][16];
  float wredsum[8][16];
  float mrow[16];
  float lrow[16];
  float srow[16];
};

// ---- precompute: E (fp32 row-major) -> E16 (fp16 row-major)
__global__ void e16_build(const float* __restrict__ E, f16* __restrict__ E16) {
  size_t i8 = (size_t)(blockIdx.x * 256 + threadIdx.x) * 8;
  float4 a = *(const float4*)(E + i8);
  float4 b = *(const float4*)(E + i8 + 4);
  f16x8 v = {(f16)a.x,(f16)a.y,(f16)a.z,(f16)a.w,
             (f16)b.x,(f16)b.y,(f16)b.z,(f16)b.w};
  *(f16x8*)(E16 + i8) = v;
}

// ---- precompute: W2[kb][d][k] = fp16(E[kb*32+k][d])  (key-major V tiles)
__global__ void w2_build(const float* __restrict__ E, f16* __restrict__ W2) {
  int kb = blockIdx.x >> 2;
  int dg = blockIdx.x & 3;
  int d  = dg * 256 + threadIdx.x;
  for (int kq = 0; kq < 4; ++kq) {
    int k0 = kq * 8;
    f16x8 v;
    #pragma unroll
    for (int j = 0; j < 8; ++j)
      v[j] = (f16)E[(size_t)(kb*32 + k0 + j) * D_DIM + d];
    *(f16x8*)(W2 + (size_t)kb * (D_DIM*32) + (size_t)d*32 + k0) = v;
  }
}

// MODE 2: K from E16, V from W2.  MODE 1: K from fp32 E, V from W2.
// MODE 0: no workspace -- K from fp32 E, V gathered direct from E (slow, correct).
template<int MODE>
__global__ __launch_bounds__(512, 2)
void cboe_attn(const float* __restrict__ X, const float* __restrict__ Eg,
               const f16* __restrict__ E16, const f16* __restrict__ W2,
               float* __restrict__ Out)
{
  extern __shared__ char smem[];
  Lds& L = *reinterpret_cast<Lds*>(smem);
  const int tid  = threadIdx.x;
  const int lane = tid & 63;
  const int w    = tid >> 6;        // wave 0..7
  const int g    = lane >> 4;       // 0..3
  const int c    = lane & 15;       // 0..15
  const int wd   = w * 128;         // this wave's D-slice base
  const int qb   = blockIdx.x * QB;
  const int sq   = tid & 15;        // softmax-phase: q index
  const int sk   = tid >> 4;        // softmax-phase: key index 0..31

  if (tid < 16) { L.mrow[tid] = -3.0e38f; L.lrow[tid] = 0.0f; }

  // Q fragments for this wave's D-slice: A[row=q=c][k-elem (g,j) = d = kc*32+8g+j]
  f16x8 aq[4];
  {
    const float* qrow = X + (size_t)(qb + c) * D_DIM + wd;
    #pragma unroll
    for (int kc = 0; kc < 4; ++kc) {
      float4 a = *(const float4*)(qrow + kc*32 + g*8);
      float4 b = *(const float4*)(qrow + kc*32 + g*8 + 4);
      aq[kc] = (f16x8){(f16)a.x,(f16)a.y,(f16)a.z,(f16)a.w,
                       (f16)b.x,(f16)b.y,(f16)b.z,(f16)b.w};
    }
  }

  f32x4 acc[8];
  #pragma unroll
  for (int i = 0; i < 8; ++i) acc[i] = (f32x4){0.f,0.f,0.f,0.f};

  __syncthreads();

  for (int it = 0; it < NITER; ++it) {
    const int kbase = it * KB;

    // issue V-tile loads (W2 -> regs) early; consumed just before B4
    float4 vreg[8];
    if (MODE >= 1) {
      const float4* src = (const float4*)(W2 + (size_t)it * (D_DIM*32));
      #pragma unroll
      for (int i = 0; i < 8; ++i) vreg[i] = src[i*512 + tid];
    }

    // ---- QK^T partials over this wave's D-slice
    f32x4 sacc[2];
    sacc[0] = (f32x4){0.f,0.f,0.f,0.f};
    sacc[1] = (f32x4){0.f,0.f,0.f,0.f};
    #pragma unroll
    for (int kt = 0; kt < 2; ++kt) {
      const size_t key = (size_t)(kbase + kt*16 + c);
      #pragma unroll
      for (int kc = 0; kc < 4; ++kc) {
        f16x8 bk;
        if (MODE == 2) {
          bk = *(const f16x8*)(E16 + key*D_DIM + wd + kc*32 + g*8);
        } else {
          const float* p = Eg + key*D_DIM + wd + kc*32 + g*8;
          float4 a = *(const float4*)p;
          float4 b = *(const float4*)(p + 4);
          bk = (f16x8){(f16)a.x,(f16)a.y,(f16)a.z,(f16)a.w,
                       (f16)b.x,(f16)b.y,(f16)b.z,(f16)b.w};
        }
        sacc[kt] = __builtin_amdgcn_mfma_f32_16x16x32_f16(aq[kc], bk, sacc[kt], 0, 0, 0);
      }
    }
    // C layout (m89): col = lane&15 (key), row = 4*(lane>>4)+r (q)
    #pragma unroll
    for (int kt = 0; kt < 2; ++kt)
      *(f32x4*)&L.Spart[w][kt*16 + c][g*4] = sacc[kt];
    __syncthreads();                                   // B1

    // ---- cross-wave reduce: thread-per-(q,key) element
    float s = 0.f;
    #pragma unroll
    for (int ww = 0; ww < 8; ++ww) s += L.Spart[ww][sk][sq];

    float r = s;
    r = fmaxf(r, __shfl_xor(r, 16));
    r = fmaxf(r, __shfl_xor(r, 32));
    if (lane < 16) L.wredmax[w][lane] = r;
    __syncthreads();                                   // B2

    if (tid < 16) {
      float mb = L.wredmax[0][tid];
      #pragma unroll
      for (int ww = 1; ww < 8; ++ww) mb = fmaxf(mb, L.wredmax[ww][tid]);
      float mo = L.mrow[tid];
      float mn = fmaxf(mo, mb);
      L.srow[tid] = __expf(mo - mn);   // 0 on first tile (mo = -3e38)
      L.mrow[tid] = mn;
    }
    __syncthreads();                                   // B3

    float p = __expf(s - L.mrow[sq]);
    L.Plds[sq][sk] = (f16)p;
    float ps = p;
    ps += __shfl_xor(ps, 16);
    ps += __shfl_xor(ps, 32);
    if (lane < 16) L.wredsum[w][lane] = ps;

    // V tile regs -> LDS (linear copy, layout identical to W2 block)
    if (MODE >= 1) {
      float4* dst = (float4*)(&L.Vs[0][0]);
      #pragma unroll
      for (int i = 0; i < 8; ++i) dst[i*512 + tid] = vreg[i];
    }
    __syncthreads();                                   // B4

    if (tid < 16) {
      float ss = L.wredsum[0][tid];
      #pragma unroll
      for (int ww = 1; ww < 8; ++ww) ss += L.wredsum[ww][tid];
      L.lrow[tid] = L.lrow[tid] * L.srow[tid] + ss;
    }

    // rescale running O by exp(m_old - m_new), rows q = 4g+r
    float scr0 = L.srow[g*4+0], scr1 = L.srow[g*4+1];
    float scr2 = L.srow[g*4+2], scr3 = L.srow[g*4+3];
    #pragma unroll
    for (int dt = 0; dt < 8; ++dt) {
      acc[dt][0] *= scr0; acc[dt][1] *= scr1;
      acc[dt][2] *= scr2; acc[dt][3] *= scr3;
    }

    // ---- PV: O[16 x 128-slice] += P[16x32] @ V[32 x 128-slice]
    f16x8 ap = *(const f16x8*)&L.Plds[c][g*8];   // A[row=q=c][k=key=8g+j]
    #pragma unroll
    for (int dt = 0; dt < 8; ++dt) {
      f16x8 bv;
      if (MODE >= 1) {
        bv = *(const f16x8*)&L.Vs[wd + dt*16 + c][g*8];  // B[k=key][col=d=c]
      } else {
        #pragma unroll
        for (int j = 0; j < 8; ++j)
          bv[j] = (f16)Eg[(size_t)(kbase + g*8 + j)*D_DIM + wd + dt*16 + c];
      }
      acc[dt] = __builtin_amdgcn_mfma_f32_16x16x32_f16(ap, bv, acc[dt], 0, 0, 0);
    }
    __syncthreads();                                   // B5
  }

  // epilogue: divide by l, store fp32
  #pragma unroll
  for (int dt = 0; dt < 8; ++dt) {
    #pragma unroll
    for (int rr = 0; rr < 4; ++rr) {
      int q = g*4 + rr;
      Out[(size_t)(qb + q)*D_DIM + wd + dt*16 + c] = acc[dt][rr] / L.lrow[q];
    }
  }
}

extern "C" void kernel_launch(void* const* d_in, const int* in_sizes, int n_in,
                              void* d_out, int out_size, void* d_ws, size_t ws_size,
                              hipStream_t stream) {
  const float* X  = (const float*)d_in[0];
  const float* Eg = (const float*)d_in[1];
  float* Out = (float*)d_out;

  const size_t needE16 = (size_t)N_DIM * D_DIM * sizeof(f16);      // 64 MiB
  const size_t needW2  = (size_t)NITER * D_DIM * 32 * sizeof(f16); // 64 MiB

  int mode = 0;
  f16* E16 = nullptr;
  f16* W2  = nullptr;
  if (d_ws && ws_size >= needE16 + needW2) {
    mode = 2;
    E16 = (f16*)d_ws;
    W2  = (f16*)((char*)d_ws + needE16);
  } else if (d_ws && ws_size >= needW2) {
    mode = 1;
    W2 = (f16*)d_ws;
  }

  if (mode >= 1) {
    w2_build<<<dim3(NITER * 4), dim3(256), 0, stream>>>(Eg, W2);
    if (mode == 2)
      e16_build<<<dim3((N_DIM * D_DIM) / (256 * 8)), dim3(256), 0, stream>>>(Eg, E16);
  }

  const int shmem = (int)sizeof(Lds);   // ~84 KiB > 64 KiB default -> opt in
  if (mode == 2) {
    hipFuncSetAttribute(reinterpret_cast<const void*>(&cboe_attn<2>),
                        hipFuncAttributeMaxDynamicSharedMemorySize, shmem);
    cboe_attn<2><<<dim3(T_DIM / QB), dim3(512), shmem, stream>>>(X, Eg, E16, W2, Out);
  } else if (mode == 1) {
    hipFuncSetAttribute(reinterpret_cast<const void*>(&cboe_attn<1>),
                        hipFuncAttributeMaxDynamicSharedMemorySize, shmem);
    cboe_attn<1><<<dim3(T_DIM / QB), dim3(512), shmem, stream>>>(X, Eg, E16, W2, Out);
  } else {
    hipFuncSetAttribute(reinterpret_cast<const void*>(&cboe_attn<0>),
                        hipFuncAttributeMaxDynamicSharedMemorySize, shmem);
    cboe_attn<0><<<dim3(T_DIM / QB), dim3(512), shmem, stream>>>(X, Eg, E16, W2, Out);
  }
}

// Round 2
// 1835.029 us; speedup vs baseline: 5.2161x; 5.2161x over previous
//
#include <hip/hip_runtime.h>
#include <stdint.h>

#define T_DIM 4096
#define N_DIM 32768
#define D_DIM 1024
#define QB 64
#define KB 32
#define KSPLIT 4
#define ITERS (N_DIM / KSPLIT / KB)   // 256 iterations per block
#define NKB_TOT (N_DIM / KB)          // 1024 key-blocks total

typedef _Float16 f16;
typedef _Float16 f16x8 __attribute__((ext_vector_type(8)));
typedef _Float16 f16x4 __attribute__((ext_vector_type(4)));
typedef float f32x4 __attribute__((ext_vector_type(4)));

// swizzle: XOR bits 2-3 of the k-index with q's bits 2-3 -> b128 ops land
// 2 lanes per bank-quad per 16-lane group (derived conflict-free)
#define SWZ(q, k0) ((k0) ^ ((((q) >> 2) & 3) << 2))

struct __align__(16) Lds {
  float Spart[8][64][40];  // 81920 B : per-wave partial scores [w][q][k swz]
  f16   P[64][40];         //  5120 B : P[q][k]
  float srow[64];          // rescale factors
};                         // 87296 B total

// ---- precompute: E (fp32 row-major) -> E16 (fp16 row-major)
__global__ void e16_build(const float* __restrict__ E, f16* __restrict__ E16) {
  size_t i8 = (size_t)(blockIdx.x * 256 + threadIdx.x) * 8;
  float4 a = *(const float4*)(E + i8);
  float4 b = *(const float4*)(E + i8 + 4);
  f16x8 v = {(f16)a.x,(f16)a.y,(f16)a.z,(f16)a.w,
             (f16)b.x,(f16)b.y,(f16)b.z,(f16)b.w};
  *(f16x8*)(E16 + i8) = v;
}

// ---- precompute: W2[kb][d][k] = fp16(E[kb*32+k][d])  (key-major V tiles)
__global__ void w2_build(const float* __restrict__ E, f16* __restrict__ W2) {
  int kb = blockIdx.x >> 2;
  int dg = blockIdx.x & 3;
  int d  = dg * 256 + threadIdx.x;
  for (int kq = 0; kq < 4; ++kq) {
    int k0 = kq * 8;
    f16x8 v;
    #pragma unroll
    for (int j = 0; j < 8; ++j)
      v[j] = (f16)E[(size_t)(kb*32 + k0 + j) * D_DIM + d];
    *(f16x8*)(W2 + (size_t)kb * (D_DIM*KB) + (size_t)d*KB + k0) = v;
  }
}

// Flash attention over a key-quarter. 8 waves; each wave owns a 128-wide
// d-slice for both QK^T partials and PV accumulation.
// Frag conventions (verified round 1): A: row=lane&15, k=(lane>>4)*8+j;
// B: col=lane&15, k=(lane>>4)*8+j; C: row=4*(lane>>4)+r, col=lane&15.
template<int USE_E16>
__global__ __launch_bounds__(512, 2)
void cboe_attn(const float* __restrict__ X, const float* __restrict__ Eg,
               const f16* __restrict__ E16, const f16* __restrict__ W2,
               f16* __restrict__ O16, float* __restrict__ ML)
{
  extern __shared__ char smem_raw[];
  Lds& L = *reinterpret_cast<Lds*>(smem_raw);
  const int tid   = threadIdx.x;
  const int lane  = tid & 63;
  const int w     = tid >> 6;       // wave 0..7
  const int c     = lane & 15;
  const int g     = lane >> 4;      // 0..3
  const int wd    = w * 128;        // wave's d-slice base
  const int qtile = blockIdx.x & 63;
  const int ks    = blockIdx.x >> 6;
  const int qb    = qtile * QB;
  const size_t key0 = (size_t)ks * (N_DIM / KSPLIT);
  const int sq    = tid >> 3;       // softmax phase: q row 0..63
  const int kslot = tid & 7;        // softmax phase: key quad 0..7

  // Q fragments (B-operand): qf[qt][kc] = X[qb+qt*16+c][wd+kc*32+g*8 ..+7]
  f16x8 qf[4][4];
  #pragma unroll
  for (int qt = 0; qt < 4; ++qt) {
    const float* qrow = X + (size_t)(qb + qt*16 + c) * D_DIM + wd;
    #pragma unroll
    for (int kc = 0; kc < 4; ++kc) {
      float4 a = *(const float4*)(qrow + kc*32 + g*8);
      float4 b = *(const float4*)(qrow + kc*32 + g*8 + 4);
      qf[qt][kc] = (f16x8){(f16)a.x,(f16)a.y,(f16)a.z,(f16)a.w,
                           (f16)b.x,(f16)b.y,(f16)b.z,(f16)b.w};
    }
  }

  f32x4 acc[4][8];
  #pragma unroll
  for (int qt = 0; qt < 4; ++qt)
    #pragma unroll
    for (int dt = 0; dt < 8; ++dt) acc[qt][dt] = (f32x4){0.f,0.f,0.f,0.f};

  float m_run = -1.0e30f, l_run = 0.0f;

  for (int it = 0; it < ITERS; ++it) {
    const size_t kb_glob = (size_t)ks * ITERS + it;
    const size_t kbase   = key0 + (size_t)it * KB;

    // ---- phase A: QK^T partials over this wave's 128-d slice
    #pragma unroll
    for (int kt = 0; kt < 2; ++kt) {
      const size_t key = kbase + kt*16 + c;      // A row = key
      f16x8 ak[4];
      #pragma unroll
      for (int kc = 0; kc < 4; ++kc) {
        if (USE_E16) {
          ak[kc] = *(const f16x8*)(E16 + key*D_DIM + wd + kc*32 + g*8);
        } else {
          const float* p = Eg + key*D_DIM + wd + kc*32 + g*8;
          float4 a = *(const float4*)p;
          float4 b = *(const float4*)(p + 4);
          ak[kc] = (f16x8){(f16)a.x,(f16)a.y,(f16)a.z,(f16)a.w,
                           (f16)b.x,(f16)b.y,(f16)b.z,(f16)b.w};
        }
      }
      f32x4 sacc[4];
      #pragma unroll
      for (int qt = 0; qt < 4; ++qt) sacc[qt] = (f32x4){0.f,0.f,0.f,0.f};
      #pragma unroll
      for (int kc = 0; kc < 4; ++kc)
        #pragma unroll
        for (int qt = 0; qt < 4; ++qt)
          sacc[qt] = __builtin_amdgcn_mfma_f32_16x16x32_f16(ak[kc], qf[qt][kc], sacc[qt], 0, 0, 0);
      // C: rows = keys kt*16+4g+r, col = q = qt*16+c
      #pragma unroll
      for (int qt = 0; qt < 4; ++qt) {
        int q = qt*16 + c;
        *(f32x4*)&L.Spart[w][q][SWZ(q, kt*16 + g*4)] = sacc[qt];
      }
    }
    __syncthreads();                               // B1

    // ---- phase B: reduce 8 partials + online softmax (8 threads per q row)
    f32x4 sv = (f32x4){0.f,0.f,0.f,0.f};
    #pragma unroll
    for (int w8 = 0; w8 < 8; ++w8)
      sv += *(const f32x4*)&L.Spart[w8][sq][SWZ(sq, kslot*4)];
    float tm = fmaxf(fmaxf(sv[0], sv[1]), fmaxf(sv[2], sv[3]));
    tm = fmaxf(tm, __shfl_xor(tm, 1));
    tm = fmaxf(tm, __shfl_xor(tm, 2));
    tm = fmaxf(tm, __shfl_xor(tm, 4));
    float mn = fmaxf(m_run, tm);
    float scale = __expf(m_run - mn);
    float p0 = __expf(sv[0] - mn), p1 = __expf(sv[1] - mn);
    float p2 = __expf(sv[2] - mn), p3 = __expf(sv[3] - mn);
    float psum = (p0 + p1) + (p2 + p3);
    psum += __shfl_xor(psum, 1);
    psum += __shfl_xor(psum, 2);
    psum += __shfl_xor(psum, 4);
    l_run = l_run * scale + psum;
    m_run = mn;
    *(f16x4*)&L.P[sq][kslot*4] = (f16x4){(f16)p0,(f16)p1,(f16)p2,(f16)p3};
    if (kslot == 0) L.srow[sq] = scale;
    __syncthreads();                               // B2

    // ---- phase C: rescale + PV (V direct from W2, coalesced)
    #pragma unroll
    for (int qt = 0; qt < 4; ++qt) {
      f32x4 sc = *(const f32x4*)&L.srow[qt*16 + g*4];  // rows 4g+r
      #pragma unroll
      for (int dt = 0; dt < 8; ++dt) {
        acc[qt][dt][0] *= sc[0]; acc[qt][dt][1] *= sc[1];
        acc[qt][dt][2] *= sc[2]; acc[qt][dt][3] *= sc[3];
      }
    }
    f16x8 ap[4];
    #pragma unroll
    for (int qt = 0; qt < 4; ++qt)
      ap[qt] = *(const f16x8*)&L.P[qt*16 + c][g*8];   // A row=q, k=key
    const f16* vbase = W2 + kb_glob * (D_DIM*KB);
    #pragma unroll
    for (int dt = 0; dt < 8; ++dt) {
      f16x8 bv = *(const f16x8*)(vbase + (size_t)(wd + dt*16 + c)*KB + g*8);
      #pragma unroll
      for (int qt = 0; qt < 4; ++qt)
        acc[qt][dt] = __builtin_amdgcn_mfma_f32_16x16x32_f16(ap[qt], bv, acc[qt][dt], 0, 0, 0);
    }
    // no barrier here: next B1 orders P/srow reads (phase C) before the
    // next iteration's P/srow writes (phase B); Spart writes (phase A)
    // touch nothing read after B2.
  }

  // ---- epilogue: write unnormalized partials + (m,l)
  if (kslot == 0) {
    size_t qg = (size_t)qb + sq;
    ML[((size_t)ks * T_DIM + qg) * 2 + 0] = m_run;
    ML[((size_t)ks * T_DIM + qg) * 2 + 1] = l_run;
  }
  #pragma unroll
  for (int qt = 0; qt < 4; ++qt)
    #pragma unroll
    for (int dt = 0; dt < 8; ++dt)
      #pragma unroll
      for (int r = 0; r < 4; ++r)
        O16[((size_t)ks * T_DIM + qb + qt*16 + 4*g + r) * D_DIM + wd + dt*16 + c] =
            (f16)acc[qt][dt][r];
}

// ---- combine KSPLIT partials: out = sum_ks e^{m_ks-M} O_ks / sum_ks l_ks e^{m_ks-M}
__global__ void combine(const f16* __restrict__ O16, const float* __restrict__ ML,
                        float* __restrict__ Out) {
  int q  = blockIdx.x;
  int d0 = threadIdx.x * 4;
  float m[KSPLIT], l[KSPLIT];
  float M = -1.0e30f;
  #pragma unroll
  for (int ks = 0; ks < KSPLIT; ++ks) {
    m[ks] = ML[((size_t)ks * T_DIM + q) * 2 + 0];
    l[ks] = ML[((size_t)ks * T_DIM + q) * 2 + 1];
    M = fmaxf(M, m[ks]);
  }
  float Lsum = 0.f, wk[KSPLIT];
  #pragma unroll
  for (int ks = 0; ks < KSPLIT; ++ks) {
    wk[ks] = __expf(m[ks] - M);
    Lsum += l[ks] * wk[ks];
  }
  float inv = 1.0f / Lsum;
  float o0 = 0.f, o1 = 0.f, o2 = 0.f, o3 = 0.f;
  #pragma unroll
  for (int ks = 0; ks < KSPLIT; ++ks) {
    f16x4 v = *(const f16x4*)(O16 + ((size_t)ks * T_DIM + q) * D_DIM + d0);
    o0 += wk[ks] * (float)v[0];
    o1 += wk[ks] * (float)v[1];
    o2 += wk[ks] * (float)v[2];
    o3 += wk[ks] * (float)v[3];
  }
  float4 o = {o0 * inv, o1 * inv, o2 * inv, o3 * inv};
  *(float4*)(Out + (size_t)q * D_DIM + d0) = o;
}

extern "C" void kernel_launch(void* const* d_in, const int* in_sizes, int n_in,
                              void* d_out, int out_size, void* d_ws, size_t ws_size,
                              hipStream_t stream) {
  const float* X  = (const float*)d_in[0];
  const float* Eg = (const float*)d_in[1];
  float* Out = (float*)d_out;

  const size_t szE16 = (size_t)N_DIM * D_DIM * sizeof(f16);            // 64 MiB
  const size_t szW2  = (size_t)NKB_TOT * D_DIM * KB * sizeof(f16);     // 64 MiB
  const size_t szO16 = (size_t)KSPLIT * T_DIM * D_DIM * sizeof(f16);   // 32 MiB
  const size_t szML  = (size_t)KSPLIT * T_DIM * 2 * sizeof(float);     // 128 KiB
  const size_t needT1 = szE16 + szW2 + szO16 + szML;
  const int use_e16 = (d_ws && ws_size >= needT1) ? 1 : 0;

  char* p = (char*)d_ws;
  f16* E16 = nullptr;
  if (use_e16) { E16 = (f16*)p; p += szE16; }
  f16*   W2  = (f16*)p;   p += szW2;
  f16*   O16 = (f16*)p;   p += szO16;
  float* ML  = (float*)p;

  w2_build<<<dim3(NKB_TOT * 4), dim3(256), 0, stream>>>(Eg, W2);
  if (use_e16)
    e16_build<<<dim3((N_DIM * D_DIM) / (256 * 8)), dim3(256), 0, stream>>>(Eg, E16);

  const int shmem = (int)sizeof(Lds);   // 87296 B > 64 KiB default -> opt in
  if (use_e16) {
    hipFuncSetAttribute(reinterpret_cast<const void*>(&cboe_attn<1>),
                        hipFuncAttributeMaxDynamicSharedMemorySize, shmem);
    cboe_attn<1><<<dim3((T_DIM / QB) * KSPLIT), dim3(512), shmem, stream>>>(
        X, Eg, E16, W2, O16, ML);
  } else {
    hipFuncSetAttribute(reinterpret_cast<const void*>(&cboe_attn<0>),
                        hipFuncAttributeMaxDynamicSharedMemorySize, shmem);
    cboe_attn<0><<<dim3((T_DIM / QB) * KSPLIT), dim3(512), shmem, stream>>>(
        X, Eg, nullptr, W2, O16, ML);
  }
  combine<<<dim3(T_DIM), dim3(256), 0, stream>>>(O16, ML, Out);
}